// Round 8
// baseline (188.257 us; speedup 1.0000x reference)
//
#include <hip/hip_runtime.h>
#include <hip/hip_bf16.h>
#include <stdint.h>

#define N_NODES 40000
#define D_FEAT 64
#define DEG 32
#define E_EDGES (N_NODES * DEG)
#define G_GRAPHS 200
#define NPG 200          // nodes per graph
#define ATT_SZ 64
#define HID 128
#define NCLS 6
#define XS 69            // padded LDS row stride: b128 reads <=2-way banked
#define SPIN_BLK 25      // last 25 k_agg blocks each classify 8 graphs

__device__ __forceinline__ float selu_f(float x) {
    const float scale = 1.0507009873554805f;
    const float alpha = 1.6732632423543772f;
    return scale * (x > 0.f ? x : alpha * (__expf(x) - 1.f));
}

__device__ __forceinline__ uint32_t f2bf(float f) {   // fp32 -> bf16 bits (RNE)
    uint32_t u = __builtin_bit_cast(uint32_t, f);
    return (u + 0x7fffu + ((u >> 16) & 1u)) >> 16;
}
__device__ __forceinline__ float bflo(uint32_t u) { return __builtin_bit_cast(float, u << 16); }
__device__ __forceinline__ float bfhi(uint32_t u) { return __builtin_bit_cast(float, u & 0xffff0000u); }

// Fused: w = a_vec @ W_att (per-block recompute), P/Q = exp(w.x), y = x @ Wlin^T (bf16-packed).
// Block: 256 thr, 64 nodes x 64 feats, thread tile 4x4, dot-product along k.
// Blocks 0..49 also zero the 200x64 pool; block 0 zeros the ticket counter.
__global__ __launch_bounds__(256) void k_node(const float* __restrict__ x,
                                              const float* __restrict__ Wlin,
                                              const float* __restrict__ Watt,
                                              const float* __restrict__ avec,
                                              float* __restrict__ P,
                                              float* __restrict__ Q,
                                              uint32_t* __restrict__ yb,
                                              float* __restrict__ pool,
                                              int* __restrict__ ctr) {
    __shared__ float xs[64 * XS];
    __shared__ float ws[64 * XS];
    __shared__ float ws_w[128];
    int tid = threadIdx.x;
    int n0 = blockIdx.x * 64;
    if (blockIdx.x < 50) pool[blockIdx.x * 256 + tid] = 0.f;
    if (blockIdx.x == 0 && tid == 0) *ctr = 0;

    const float4* x4 = (const float4*)(x + (size_t)n0 * 64);
    const float4* W4 = (const float4*)Wlin;
#pragma unroll
    for (int s = 0; s < 4; ++s) {
        int idx = tid + s * 256, r = idx >> 4, kk = idx & 15;
        *(float4*)&xs[r * XS + kk * 4] = x4[idx];
        *(float4*)&ws[r * XS + kk * 4] = W4[idx];
    }
    if (tid < 128) {                      // w[j] = sum_k avec[k]*Watt[k][j]
        float s = 0.f;
        for (int k = 0; k < ATT_SZ; ++k) s += avec[k] * Watt[k * 128 + tid];
        ws_w[tid] = s;
    }
    __syncthreads();

    {   // P/Q: 4 lanes per node, 16 k each
        int node = tid >> 2, part = tid & 3;
        float s1 = 0.f, s2 = 0.f;
#pragma unroll
        for (int i = 0; i < 16; ++i) {
            int k = part * 16 + i;
            float xv = xs[node * XS + k];
            s1 += xv * ws_w[k];
            s2 += xv * ws_w[64 + k];
        }
        s1 += __shfl_xor(s1, 1, 64); s1 += __shfl_xor(s1, 2, 64);
        s2 += __shfl_xor(s2, 1, 64); s2 += __shfl_xor(s2, 2, 64);
        if (part == 0) { P[n0 + node] = __expf(s1); Q[n0 + node] = __expf(s2); }
    }

    int tm = tid >> 4, tf = tid & 15;
    float acc[4][4];
#pragma unroll
    for (int i = 0; i < 4; ++i)
#pragma unroll
        for (int j = 0; j < 4; ++j) acc[i][j] = 0.f;
#pragma unroll
    for (int kk = 0; kk < 16; ++kk) {
        float4 xv[4], wv[4];
#pragma unroll
        for (int i = 0; i < 4; ++i) xv[i] = *(const float4*)&xs[(tm + 16 * i) * XS + kk * 4];
#pragma unroll
        for (int j = 0; j < 4; ++j) wv[j] = *(const float4*)&ws[(4 * tf + j) * XS + kk * 4];
#pragma unroll
        for (int i = 0; i < 4; ++i)
#pragma unroll
            for (int j = 0; j < 4; ++j)
                acc[i][j] += xv[i].x * wv[j].x + xv[i].y * wv[j].y
                           + xv[i].z * wv[j].z + xv[i].w * wv[j].w;
    }
#pragma unroll
    for (int i = 0; i < 4; ++i) {
        int m = n0 + tm + 16 * i;
        uint32_t p0 = f2bf(acc[i][0]) | (f2bf(acc[i][1]) << 16);
        uint32_t p1 = f2bf(acc[i][2]) | (f2bf(acc[i][3]) << 16);
        *(uint2*)&yb[(size_t)m * 32 + tf * 2] = make_uint2(p0, p1);
    }
}

// V[n] = P[n] / (Q[n] * sum_{e in [32n,32n+32)} P[row[e]])
__global__ __launch_bounds__(256) void k_edges(const int* __restrict__ row,
                                               const float* __restrict__ P,
                                               const float* __restrict__ Q,
                                               float* __restrict__ V) {
    int e = blockIdx.x * 256 + threadIdx.x;
    float p = P[row[e]];
#pragma unroll
    for (int off = 16; off; off >>= 1)
        p += __shfl_xor(p, off, 32);
    if ((threadIdx.x & 31) == 0) {
        int n = e >> 5;
        V[n] = P[n] / (Q[n] * p);
    }
}

// h[n][:] = selu( Q[n]/32 * sum_j V[r_j]*y[r_j][:] + b_lin ), pooled by graph.
// Block = 32 nodes. 1024 edge records (V[r], r*128) staged in LDS. Wave: 8 nodes;
// quarter q gathers row s*4+q as uint2 (16 lanes x 8B = 128B row; 4 rows/instr).
// Epilogue: every block tickets; last SPIN_BLK blocks spin (acquire) and run the
// classifier (k_cls folded in), 8 graphs each.
__global__ __launch_bounds__(256) void k_agg(const int* __restrict__ row,
                                             const float* __restrict__ V,
                                             const float* __restrict__ Q,
                                             const uint32_t* __restrict__ yb,
                                             const float* __restrict__ blin,
                                             float* __restrict__ pool,
                                             const float* __restrict__ W1,
                                             const float* __restrict__ b1,
                                             const float* __restrict__ W2,
                                             const float* __restrict__ b2,
                                             float* __restrict__ out,
                                             int* __restrict__ ctr) {
    __shared__ float2 meta[1024];        // (V[r], bitcast(r*128))
    __shared__ int tick_s;
    int tid = threadIdx.x;
    int n0 = blockIdx.x * 32;

    int4 r4 = ((const int4*)(row + (size_t)n0 * 32))[tid];
    meta[4 * tid + 0] = make_float2(V[r4.x], __builtin_bit_cast(float, r4.x << 7));
    meta[4 * tid + 1] = make_float2(V[r4.y], __builtin_bit_cast(float, r4.y << 7));
    meta[4 * tid + 2] = make_float2(V[r4.z], __builtin_bit_cast(float, r4.z << 7));
    meta[4 * tid + 3] = make_float2(V[r4.w], __builtin_bit_cast(float, r4.w << 7));
    __syncthreads();

    int wv = tid >> 6, lane = tid & 63;
    int q = lane >> 4, fi = lane & 15;
    float4 bl4 = ((const float4*)blin)[fi];
    int nw0 = n0 + wv * 8;               // 8 aligned nodes: one graph (8 | 200)
    float4 pacc = make_float4(0.f, 0.f, 0.f, 0.f);
    const char* ybc = (const char*)yb;
#pragma unroll 1
    for (int nn = 0; nn < 8; ++nn) {
        int n = nw0 + nn;
        int base = (wv * 8 + nn) * 32;
        float4 a = make_float4(0.f, 0.f, 0.f, 0.f);
#pragma unroll
        for (int s = 0; s < 8; ++s) {
            float2 m = meta[base + s * 4 + q];
            uint32_t rbyte = __builtin_bit_cast(uint32_t, m.y);
            uint2 u = *(const uint2*)(ybc + rbyte + fi * 8);
            a.x += m.x * bflo(u.x);
            a.y += m.x * bfhi(u.x);
            a.z += m.x * bflo(u.y);
            a.w += m.x * bfhi(u.y);
        }
        a.x += __shfl_xor(a.x, 16, 64); a.x += __shfl_xor(a.x, 32, 64);
        a.y += __shfl_xor(a.y, 16, 64); a.y += __shfl_xor(a.y, 32, 64);
        a.z += __shfl_xor(a.z, 16, 64); a.z += __shfl_xor(a.z, 32, 64);
        a.w += __shfl_xor(a.w, 16, 64); a.w += __shfl_xor(a.w, 32, 64);
        float qn = Q[n] * (1.f / 32.f);
        pacc.x += selu_f(qn * a.x + bl4.x);
        pacc.y += selu_f(qn * a.y + bl4.y);
        pacc.z += selu_f(qn * a.z + bl4.z);
        pacc.w += selu_f(qn * a.w + bl4.w);
    }
    if (q == 0) {
        int g = nw0 / NPG;
        float* pp = &pool[g * 64 + 4 * fi];
        atomicAdd(pp + 0, pacc.x);
        atomicAdd(pp + 1, pacc.y);
        atomicAdd(pp + 2, pacc.z);
        atomicAdd(pp + 3, pacc.w);
    }

    // ---- classifier epilogue (k_cls folded in) ----
    __syncthreads();                      // drain this block's atomics (vmcnt)
    if (tid == 0) {
        __threadfence();                  // release: pool updates ordered before ticket
        tick_s = atomicAdd(ctr, 1);
    }
    __syncthreads();
    int ticket = tick_s;
    int nblk = gridDim.x;
    if (ticket < nblk - SPIN_BLK) return;
    if (tid == 0) {
        while (__hip_atomic_load(ctr, __ATOMIC_ACQUIRE, __HIP_MEMORY_SCOPE_AGENT) < nblk)
            __builtin_amdgcn_s_sleep(1);
    }
    __syncthreads();
    int slot = ticket - (nblk - SPIN_BLK);
    float* ps = (float*)meta;            // meta is dead; reuse LDS
    float* hc = ps + 64;
    float* lg = ps + 192;
    for (int gi = 0; gi < 8; ++gi) {
        int g = slot * 8 + gi;
        if (tid < 64)
            ps[tid] = __hip_atomic_load(&pool[g * 64 + tid], __ATOMIC_RELAXED,
                                        __HIP_MEMORY_SCOPE_AGENT) * (1.f / NPG);
        __syncthreads();
        if (tid < HID) {
            float s = b1[tid];
            for (int k = 0; k < 64; ++k) s += W1[tid * 64 + k] * ps[k];
            hc[tid] = selu_f(s);
        }
        __syncthreads();
        if (tid < NCLS) {
            float l = b2[tid];
            for (int k = 0; k < HID; ++k) l += W2[tid * 128 + k] * hc[k];
            lg[tid] = l;
        }
        __syncthreads();
        if (tid == 0) {
            float m = lg[0];
            for (int c = 1; c < NCLS; ++c) m = fmaxf(m, lg[c]);
            float ex[NCLS], sum = 0.f;
            for (int c = 0; c < NCLS; ++c) { ex[c] = __expf(lg[c] - m); sum += ex[c]; }
            for (int c = 0; c < NCLS; ++c) out[g * NCLS + c] = ex[c] / sum;
        }
        __syncthreads();
    }
}

extern "C" void kernel_launch(void* const* d_in, const int* in_sizes, int n_in,
                              void* d_out, int out_size, void* d_ws, size_t ws_size,
                              hipStream_t stream) {
    const float* x    = (const float*)d_in[0];
    const float* Wlin = (const float*)d_in[1];
    const float* blin = (const float*)d_in[2];
    const float* Watt = (const float*)d_in[3];
    const float* avec = (const float*)d_in[4];
    const float* W1   = (const float*)d_in[5];
    const float* b1   = (const float*)d_in[6];
    const float* W2   = (const float*)d_in[7];
    const float* b2   = (const float*)d_in[8];
    const int*   row  = (const int*)d_in[9];   // edge_index[0]; edge_index[1] is structured
    float* out = (float*)d_out;

    // ws layout: P[N] | Q[N] | V[N] | pool[200*64] | yb[N*32 u32 (bf16x2 y)] | ctr
    float* P    = (float*)d_ws;
    float* Q    = P + N_NODES;
    float* V    = Q + N_NODES;
    float* pool = V + N_NODES;
    uint32_t* yb = (uint32_t*)(pool + G_GRAPHS * 64);
    int* ctr    = (int*)(yb + (size_t)N_NODES * 32);

    k_node<<<N_NODES / 64, 256, 0, stream>>>(x, Wlin, Watt, avec, P, Q, yb, pool, ctr);
    k_edges<<<E_EDGES / 256, 256, 0, stream>>>(row, P, Q, V);
    k_agg<<<N_NODES / 32, 256, 0, stream>>>(row, V, Q, yb, blin, pool,
                                            W1, b1, W2, b2, out, ctr);
}

// Round 9
// 141.568 us; speedup vs baseline: 1.3298x; 1.3298x over previous
//
#include <hip/hip_runtime.h>
#include <hip/hip_bf16.h>
#include <stdint.h>

#define N_NODES 40000
#define D_FEAT 64
#define DEG 32
#define E_EDGES (N_NODES * DEG)
#define G_GRAPHS 200
#define NPG 200          // nodes per graph
#define ATT_SZ 64
#define HID 128
#define NCLS 6
#define XS 69            // padded LDS row stride: b128 reads <=2-way banked

__device__ __forceinline__ float selu_f(float x) {
    const float scale = 1.0507009873554805f;
    const float alpha = 1.6732632423543772f;
    return scale * (x > 0.f ? x : alpha * (__expf(x) - 1.f));
}

__device__ __forceinline__ uint32_t f2bf(float f) {   // fp32 -> bf16 bits (RNE)
    uint32_t u = __builtin_bit_cast(uint32_t, f);
    return (u + 0x7fffu + ((u >> 16) & 1u)) >> 16;
}
__device__ __forceinline__ float bflo(uint32_t u) { return __builtin_bit_cast(float, u << 16); }
__device__ __forceinline__ float bfhi(uint32_t u) { return __builtin_bit_cast(float, u & 0xffff0000u); }

// Fused: w = a_vec @ W_att (per-block recompute), P/Q = exp(w.x), y = x @ Wlin^T (bf16-packed).
// Block: 256 thr, 64 nodes x 64 feats, thread tile 4x4, dot-product along k.
// Blocks 0..49 also zero the 200x64 pool (harness poisons ws with 0xAA).
__global__ __launch_bounds__(256) void k_node(const float* __restrict__ x,
                                              const float* __restrict__ Wlin,
                                              const float* __restrict__ Watt,
                                              const float* __restrict__ avec,
                                              float* __restrict__ P,
                                              float* __restrict__ Q,
                                              uint32_t* __restrict__ yb,
                                              float* __restrict__ pool) {
    __shared__ float xs[64 * XS];
    __shared__ float ws[64 * XS];
    __shared__ float ws_w[128];
    int tid = threadIdx.x;
    int n0 = blockIdx.x * 64;
    if (blockIdx.x < 50) pool[blockIdx.x * 256 + tid] = 0.f;

    const float4* x4 = (const float4*)(x + (size_t)n0 * 64);
    const float4* W4 = (const float4*)Wlin;
#pragma unroll
    for (int s = 0; s < 4; ++s) {
        int idx = tid + s * 256, r = idx >> 4, kk = idx & 15;
        *(float4*)&xs[r * XS + kk * 4] = x4[idx];
        *(float4*)&ws[r * XS + kk * 4] = W4[idx];
    }
    if (tid < 128) {                      // w[j] = sum_k avec[k]*Watt[k][j]
        float s = 0.f;
        for (int k = 0; k < ATT_SZ; ++k) s += avec[k] * Watt[k * 128 + tid];
        ws_w[tid] = s;
    }
    __syncthreads();

    {   // P/Q: 4 lanes per node, 16 k each
        int node = tid >> 2, part = tid & 3;
        float s1 = 0.f, s2 = 0.f;
#pragma unroll
        for (int i = 0; i < 16; ++i) {
            int k = part * 16 + i;
            float xv = xs[node * XS + k];
            s1 += xv * ws_w[k];
            s2 += xv * ws_w[64 + k];
        }
        s1 += __shfl_xor(s1, 1, 64); s1 += __shfl_xor(s1, 2, 64);
        s2 += __shfl_xor(s2, 1, 64); s2 += __shfl_xor(s2, 2, 64);
        if (part == 0) { P[n0 + node] = __expf(s1); Q[n0 + node] = __expf(s2); }
    }

    int tm = tid >> 4, tf = tid & 15;
    float acc[4][4];
#pragma unroll
    for (int i = 0; i < 4; ++i)
#pragma unroll
        for (int j = 0; j < 4; ++j) acc[i][j] = 0.f;
#pragma unroll
    for (int kk = 0; kk < 16; ++kk) {
        float4 xv[4], wv[4];
#pragma unroll
        for (int i = 0; i < 4; ++i) xv[i] = *(const float4*)&xs[(tm + 16 * i) * XS + kk * 4];
#pragma unroll
        for (int j = 0; j < 4; ++j) wv[j] = *(const float4*)&ws[(4 * tf + j) * XS + kk * 4];
#pragma unroll
        for (int i = 0; i < 4; ++i)
#pragma unroll
            for (int j = 0; j < 4; ++j)
                acc[i][j] += xv[i].x * wv[j].x + xv[i].y * wv[j].y
                           + xv[i].z * wv[j].z + xv[i].w * wv[j].w;
    }
#pragma unroll
    for (int i = 0; i < 4; ++i) {
        int m = n0 + tm + 16 * i;
        uint32_t p0 = f2bf(acc[i][0]) | (f2bf(acc[i][1]) << 16);
        uint32_t p1 = f2bf(acc[i][2]) | (f2bf(acc[i][3]) << 16);
        *(uint2*)&yb[(size_t)m * 32 + tf * 2] = make_uint2(p0, p1);
    }
}

// V[n] = P[n] / (Q[n] * sum_{e in [32n,32n+32)} P[row[e]])
__global__ __launch_bounds__(256) void k_edges(const int* __restrict__ row,
                                               const float* __restrict__ P,
                                               const float* __restrict__ Q,
                                               float* __restrict__ V) {
    int e = blockIdx.x * 256 + threadIdx.x;
    float p = P[row[e]];
#pragma unroll
    for (int off = 16; off; off >>= 1)
        p += __shfl_xor(p, off, 32);
    if ((threadIdx.x & 31) == 0) {
        int n = e >> 5;
        V[n] = P[n] / (Q[n] * p);
    }
}

// h[n][:] = selu( Q[n]/32 * sum_j V[r_j]*y[r_j][:] + b_lin ), pooled by graph.
// Block = 32 nodes. 1024 edge records (V[r], r*128) staged in LDS. Wave: 8 nodes;
// quarter q gathers row s*4+q as uint2 (16 lanes x 8B = 128B row; 4 rows/instr).
// unroll 4: ~32 independent gathers in flight per wave (kernel is latency-bound:
// R8 counters showed FETCH 29MB for a 164MB gather stream -> L2/LLC-hit, MLP-starved).
__global__ __launch_bounds__(256) void k_agg(const int* __restrict__ row,
                                             const float* __restrict__ V,
                                             const float* __restrict__ Q,
                                             const uint32_t* __restrict__ yb,
                                             const float* __restrict__ blin,
                                             float* __restrict__ pool) {
    __shared__ float2 meta[1024];        // (V[r], bitcast(r*128))
    int tid = threadIdx.x;
    int n0 = blockIdx.x * 32;

    int4 r4 = ((const int4*)(row + (size_t)n0 * 32))[tid];
    meta[4 * tid + 0] = make_float2(V[r4.x], __builtin_bit_cast(float, r4.x << 7));
    meta[4 * tid + 1] = make_float2(V[r4.y], __builtin_bit_cast(float, r4.y << 7));
    meta[4 * tid + 2] = make_float2(V[r4.z], __builtin_bit_cast(float, r4.z << 7));
    meta[4 * tid + 3] = make_float2(V[r4.w], __builtin_bit_cast(float, r4.w << 7));
    __syncthreads();

    int wv = tid >> 6, lane = tid & 63;
    int q = lane >> 4, fi = lane & 15;
    float4 bl4 = ((const float4*)blin)[fi];
    int nw0 = n0 + wv * 8;               // 8 aligned nodes: one graph (8 | 200)
    float4 pacc = make_float4(0.f, 0.f, 0.f, 0.f);
    const char* ybc = (const char*)yb;
#pragma unroll 4
    for (int nn = 0; nn < 8; ++nn) {
        int n = nw0 + nn;
        int base = (wv * 8 + nn) * 32;
        float4 a = make_float4(0.f, 0.f, 0.f, 0.f);
#pragma unroll
        for (int s = 0; s < 8; ++s) {
            float2 m = meta[base + s * 4 + q];
            uint32_t rbyte = __builtin_bit_cast(uint32_t, m.y);
            uint2 u = *(const uint2*)(ybc + rbyte + fi * 8);
            a.x += m.x * bflo(u.x);
            a.y += m.x * bfhi(u.x);
            a.z += m.x * bflo(u.y);
            a.w += m.x * bfhi(u.y);
        }
        a.x += __shfl_xor(a.x, 16, 64); a.x += __shfl_xor(a.x, 32, 64);
        a.y += __shfl_xor(a.y, 16, 64); a.y += __shfl_xor(a.y, 32, 64);
        a.z += __shfl_xor(a.z, 16, 64); a.z += __shfl_xor(a.z, 32, 64);
        a.w += __shfl_xor(a.w, 16, 64); a.w += __shfl_xor(a.w, 32, 64);
        float qn = Q[n] * (1.f / 32.f);
        pacc.x += selu_f(qn * a.x + bl4.x);
        pacc.y += selu_f(qn * a.y + bl4.y);
        pacc.z += selu_f(qn * a.z + bl4.z);
        pacc.w += selu_f(qn * a.w + bl4.w);
    }
    if (q == 0) {
        int g = nw0 / NPG;
        float* pp = &pool[g * 64 + 4 * fi];
        atomicAdd(pp + 0, pacc.x);
        atomicAdd(pp + 1, pacc.y);
        atomicAdd(pp + 2, pacc.z);
        atomicAdd(pp + 3, pacc.w);
    }
}

// pooled = pool/200; hcls = selu(W1 @ pooled + b1); logits = W2 @ hcls + b2; softmax
__global__ __launch_bounds__(128) void k_cls(const float* __restrict__ pool,
                                             const float* __restrict__ W1,
                                             const float* __restrict__ b1,
                                             const float* __restrict__ W2,
                                             const float* __restrict__ b2,
                                             float* __restrict__ out) {
    __shared__ float ps[64];
    __shared__ float hc[HID];
    __shared__ float lg[NCLS];
    int t = threadIdx.x, g = blockIdx.x;
    if (t < 64) ps[t] = pool[g * 64 + t] * (1.f / NPG);
    __syncthreads();
    float s = b1[t];
    for (int k = 0; k < 64; ++k)
        s += W1[t * 64 + k] * ps[k];
    hc[t] = selu_f(s);
    __syncthreads();
    if (t < NCLS) {
        float l = b2[t];
        for (int k = 0; k < HID; ++k)
            l += W2[t * 128 + k] * hc[k];
        lg[t] = l;
    }
    __syncthreads();
    if (t == 0) {
        float m = lg[0];
        for (int c = 1; c < NCLS; ++c) m = fmaxf(m, lg[c]);
        float ex[NCLS], sum = 0.f;
        for (int c = 0; c < NCLS; ++c) { ex[c] = __expf(lg[c] - m); sum += ex[c]; }
        for (int c = 0; c < NCLS; ++c) out[g * NCLS + c] = ex[c] / sum;
    }
}

extern "C" void kernel_launch(void* const* d_in, const int* in_sizes, int n_in,
                              void* d_out, int out_size, void* d_ws, size_t ws_size,
                              hipStream_t stream) {
    const float* x    = (const float*)d_in[0];
    const float* Wlin = (const float*)d_in[1];
    const float* blin = (const float*)d_in[2];
    const float* Watt = (const float*)d_in[3];
    const float* avec = (const float*)d_in[4];
    const float* W1   = (const float*)d_in[5];
    const float* b1   = (const float*)d_in[6];
    const float* W2   = (const float*)d_in[7];
    const float* b2   = (const float*)d_in[8];
    const int*   row  = (const int*)d_in[9];   // edge_index[0]; edge_index[1] is structured
    float* out = (float*)d_out;

    // ws layout: P[N] | Q[N] | V[N] | pool[200*64] | yb[N*32 u32 (bf16x2 y)]
    float* P    = (float*)d_ws;
    float* Q    = P + N_NODES;
    float* V    = Q + N_NODES;
    float* pool = V + N_NODES;
    uint32_t* yb = (uint32_t*)(pool + G_GRAPHS * 64);

    k_node<<<N_NODES / 64, 256, 0, stream>>>(x, Wlin, Watt, avec, P, Q, yb, pool);
    k_edges<<<E_EDGES / 256, 256, 0, stream>>>(row, P, Q, V);
    k_agg<<<N_NODES / 32, 256, 0, stream>>>(row, V, Q, yb, blin, pool);
    k_cls<<<G_GRAPHS, 128, 0, stream>>>(pool, W1, b1, W2, b2, out);
}

// Round 10
// 133.076 us; speedup vs baseline: 1.4147x; 1.0638x over previous
//
#include <hip/hip_runtime.h>
#include <hip/hip_bf16.h>
#include <stdint.h>

#define N_NODES 40000
#define D_FEAT 64
#define DEG 32
#define E_EDGES (N_NODES * DEG)
#define G_GRAPHS 200
#define NPG 200          // nodes per graph
#define ATT_SZ 64
#define HID 128
#define NCLS 6
#define XS 69            // padded LDS row stride: b128 reads <=2-way banked

__device__ __forceinline__ float selu_f(float x) {
    const float scale = 1.0507009873554805f;
    const float alpha = 1.6732632423543772f;
    return scale * (x > 0.f ? x : alpha * (__expf(x) - 1.f));
}

__device__ __forceinline__ uint32_t f2bf(float f) {   // fp32 -> bf16 bits (RNE)
    uint32_t u = __builtin_bit_cast(uint32_t, f);
    return (u + 0x7fffu + ((u >> 16) & 1u)) >> 16;
}
__device__ __forceinline__ float bflo(uint32_t u) { return __builtin_bit_cast(float, u << 16); }
__device__ __forceinline__ float bfhi(uint32_t u) { return __builtin_bit_cast(float, u & 0xffff0000u); }

// Fused: w = a_vec @ W_att (per-block recompute), P/Q = exp(w.x), y = x @ Wlin^T (bf16-packed).
// Block: 256 thr, 64 nodes x 64 feats, thread tile 4x4, dot-product along k.
// Blocks 0..49 also zero the 200x64 pool (harness poisons ws with 0xAA).
__global__ __launch_bounds__(256) void k_node(const float* __restrict__ x,
                                              const float* __restrict__ Wlin,
                                              const float* __restrict__ Watt,
                                              const float* __restrict__ avec,
                                              float* __restrict__ P,
                                              float* __restrict__ Q,
                                              uint32_t* __restrict__ yb,
                                              float* __restrict__ pool) {
    __shared__ float xs[64 * XS];
    __shared__ float ws[64 * XS];
    __shared__ float ws_w[128];
    int tid = threadIdx.x;
    int n0 = blockIdx.x * 64;
    if (blockIdx.x < 50) pool[blockIdx.x * 256 + tid] = 0.f;

    const float4* x4 = (const float4*)(x + (size_t)n0 * 64);
    const float4* W4 = (const float4*)Wlin;
#pragma unroll
    for (int s = 0; s < 4; ++s) {
        int idx = tid + s * 256, r = idx >> 4, kk = idx & 15;
        *(float4*)&xs[r * XS + kk * 4] = x4[idx];
        *(float4*)&ws[r * XS + kk * 4] = W4[idx];
    }
    if (tid < 128) {                      // w[j] = sum_k avec[k]*Watt[k][j]
        float s = 0.f;
        for (int k = 0; k < ATT_SZ; ++k) s += avec[k] * Watt[k * 128 + tid];
        ws_w[tid] = s;
    }
    __syncthreads();

    {   // P/Q: 4 lanes per node, 16 k each
        int node = tid >> 2, part = tid & 3;
        float s1 = 0.f, s2 = 0.f;
#pragma unroll
        for (int i = 0; i < 16; ++i) {
            int k = part * 16 + i;
            float xv = xs[node * XS + k];
            s1 += xv * ws_w[k];
            s2 += xv * ws_w[64 + k];
        }
        s1 += __shfl_xor(s1, 1, 64); s1 += __shfl_xor(s1, 2, 64);
        s2 += __shfl_xor(s2, 1, 64); s2 += __shfl_xor(s2, 2, 64);
        if (part == 0) { P[n0 + node] = __expf(s1); Q[n0 + node] = __expf(s2); }
    }

    int tm = tid >> 4, tf = tid & 15;
    float acc[4][4];
#pragma unroll
    for (int i = 0; i < 4; ++i)
#pragma unroll
        for (int j = 0; j < 4; ++j) acc[i][j] = 0.f;
#pragma unroll
    for (int kk = 0; kk < 16; ++kk) {
        float4 xv[4], wv[4];
#pragma unroll
        for (int i = 0; i < 4; ++i) xv[i] = *(const float4*)&xs[(tm + 16 * i) * XS + kk * 4];
#pragma unroll
        for (int j = 0; j < 4; ++j) wv[j] = *(const float4*)&ws[(4 * tf + j) * XS + kk * 4];
#pragma unroll
        for (int i = 0; i < 4; ++i)
#pragma unroll
            for (int j = 0; j < 4; ++j)
                acc[i][j] += xv[i].x * wv[j].x + xv[i].y * wv[j].y
                           + xv[i].z * wv[j].z + xv[i].w * wv[j].w;
    }
#pragma unroll
    for (int i = 0; i < 4; ++i) {
        int m = n0 + tm + 16 * i;
        uint32_t p0 = f2bf(acc[i][0]) | (f2bf(acc[i][1]) << 16);
        uint32_t p1 = f2bf(acc[i][2]) | (f2bf(acc[i][3]) << 16);
        *(uint2*)&yb[(size_t)m * 32 + tf * 2] = make_uint2(p0, p1);
    }
}

// V[n] = P[n] / (Q[n] * sum_{e in [32n,32n+32)} P[row[e]])
__global__ __launch_bounds__(256) void k_edges(const int* __restrict__ row,
                                               const float* __restrict__ P,
                                               const float* __restrict__ Q,
                                               float* __restrict__ V) {
    int e = blockIdx.x * 256 + threadIdx.x;
    float p = P[row[e]];
#pragma unroll
    for (int off = 16; off; off >>= 1)
        p += __shfl_xor(p, off, 32);
    if ((threadIdx.x & 31) == 0) {
        int n = e >> 5;
        V[n] = P[n] / (Q[n] * p);
    }
}

// h[n][:] = selu( Q[n]/32 * sum_j V[r_j]*y[r_j][:] + b_lin ), pooled by graph.
// Block = 32 nodes. 1024 edge records (V[r], r*128) staged in LDS. Wave: 8 nodes;
// quarter q gathers row s*4+q as uint2 (16 lanes x 8B = 128B row; 4 rows/instr).
// Serialized node loop (unroll 1): measured best — the kernel sits at the ~6.6 TB/s
// random-gather BW ceiling (R3 fp32: 327MB/48.7us; R6 bf16: 164MB/~25us), so extra
// MLP (R9 unroll4) only adds VGPR pressure.
__global__ __launch_bounds__(256) void k_agg(const int* __restrict__ row,
                                             const float* __restrict__ V,
                                             const float* __restrict__ Q,
                                             const uint32_t* __restrict__ yb,
                                             const float* __restrict__ blin,
                                             float* __restrict__ pool) {
    __shared__ float2 meta[1024];        // (V[r], bitcast(r*128))
    int tid = threadIdx.x;
    int n0 = blockIdx.x * 32;

    int4 r4 = ((const int4*)(row + (size_t)n0 * 32))[tid];
    meta[4 * tid + 0] = make_float2(V[r4.x], __builtin_bit_cast(float, r4.x << 7));
    meta[4 * tid + 1] = make_float2(V[r4.y], __builtin_bit_cast(float, r4.y << 7));
    meta[4 * tid + 2] = make_float2(V[r4.z], __builtin_bit_cast(float, r4.z << 7));
    meta[4 * tid + 3] = make_float2(V[r4.w], __builtin_bit_cast(float, r4.w << 7));
    __syncthreads();

    int wv = tid >> 6, lane = tid & 63;
    int q = lane >> 4, fi = lane & 15;
    float4 bl4 = ((const float4*)blin)[fi];
    int nw0 = n0 + wv * 8;               // 8 aligned nodes: one graph (8 | 200)
    float4 pacc = make_float4(0.f, 0.f, 0.f, 0.f);
    const char* ybc = (const char*)yb;
#pragma unroll 1
    for (int nn = 0; nn < 8; ++nn) {
        int n = nw0 + nn;
        int base = (wv * 8 + nn) * 32;
        float4 a = make_float4(0.f, 0.f, 0.f, 0.f);
#pragma unroll
        for (int s = 0; s < 8; ++s) {
            float2 m = meta[base + s * 4 + q];
            uint32_t rbyte = __builtin_bit_cast(uint32_t, m.y);
            uint2 u = *(const uint2*)(ybc + rbyte + fi * 8);
            a.x += m.x * bflo(u.x);
            a.y += m.x * bfhi(u.x);
            a.z += m.x * bflo(u.y);
            a.w += m.x * bfhi(u.y);
        }
        a.x += __shfl_xor(a.x, 16, 64); a.x += __shfl_xor(a.x, 32, 64);
        a.y += __shfl_xor(a.y, 16, 64); a.y += __shfl_xor(a.y, 32, 64);
        a.z += __shfl_xor(a.z, 16, 64); a.z += __shfl_xor(a.z, 32, 64);
        a.w += __shfl_xor(a.w, 16, 64); a.w += __shfl_xor(a.w, 32, 64);
        float qn = Q[n] * (1.f / 32.f);
        pacc.x += selu_f(qn * a.x + bl4.x);
        pacc.y += selu_f(qn * a.y + bl4.y);
        pacc.z += selu_f(qn * a.z + bl4.z);
        pacc.w += selu_f(qn * a.w + bl4.w);
    }
    if (q == 0) {
        int g = nw0 / NPG;
        float* pp = &pool[g * 64 + 4 * fi];
        atomicAdd(pp + 0, pacc.x);
        atomicAdd(pp + 1, pacc.y);
        atomicAdd(pp + 2, pacc.z);
        atomicAdd(pp + 3, pacc.w);
    }
}

// pooled = pool/200; hcls = selu(W1 @ pooled + b1); logits = W2 @ hcls + b2; softmax
__global__ __launch_bounds__(128) void k_cls(const float* __restrict__ pool,
                                             const float* __restrict__ W1,
                                             const float* __restrict__ b1,
                                             const float* __restrict__ W2,
                                             const float* __restrict__ b2,
                                             float* __restrict__ out) {
    __shared__ float ps[64];
    __shared__ float hc[HID];
    __shared__ float lg[NCLS];
    int t = threadIdx.x, g = blockIdx.x;
    if (t < 64) ps[t] = pool[g * 64 + t] * (1.f / NPG);
    __syncthreads();
    float s = b1[t];
    for (int k = 0; k < 64; ++k)
        s += W1[t * 64 + k] * ps[k];
    hc[t] = selu_f(s);
    __syncthreads();
    if (t < NCLS) {
        float l = b2[t];
        for (int k = 0; k < HID; ++k)
            l += W2[t * 128 + k] * hc[k];
        lg[t] = l;
    }
    __syncthreads();
    if (t == 0) {
        float m = lg[0];
        for (int c = 1; c < NCLS; ++c) m = fmaxf(m, lg[c]);
        float ex[NCLS], sum = 0.f;
        for (int c = 0; c < NCLS; ++c) { ex[c] = __expf(lg[c] - m); sum += ex[c]; }
        for (int c = 0; c < NCLS; ++c) out[g * NCLS + c] = ex[c] / sum;
    }
}

extern "C" void kernel_launch(void* const* d_in, const int* in_sizes, int n_in,
                              void* d_out, int out_size, void* d_ws, size_t ws_size,
                              hipStream_t stream) {
    const float* x    = (const float*)d_in[0];
    const float* Wlin = (const float*)d_in[1];
    const float* blin = (const float*)d_in[2];
    const float* Watt = (const float*)d_in[3];
    const float* avec = (const float*)d_in[4];
    const float* W1   = (const float*)d_in[5];
    const float* b1   = (const float*)d_in[6];
    const float* W2   = (const float*)d_in[7];
    const float* b2   = (const float*)d_in[8];
    const int*   row  = (const int*)d_in[9];   // edge_index[0]; edge_index[1] is structured
    float* out = (float*)d_out;

    // ws layout: P[N] | Q[N] | V[N] | pool[200*64] | yb[N*32 u32 (bf16x2 y)]
    float* P    = (float*)d_ws;
    float* Q    = P + N_NODES;
    float* V    = Q + N_NODES;
    float* pool = V + N_NODES;
    uint32_t* yb = (uint32_t*)(pool + G_GRAPHS * 64);

    k_node<<<N_NODES / 64, 256, 0, stream>>>(x, Wlin, Watt, avec, P, Q, yb, pool);
    k_edges<<<E_EDGES / 256, 256, 0, stream>>>(row, P, Q, V);
    k_agg<<<N_NODES / 32, 256, 0, stream>>>(row, V, Q, yb, blin, pool);
    k_cls<<<G_GRAPHS, 128, 0, stream>>>(pool, W1, b1, W2, b2, out);
}